// Round 1
// baseline (262.335 us; speedup 1.0000x reference)
//
#include <hip/hip_runtime.h>
#include <math.h>

#define EPS 1e-5f

typedef _Float16 half4 __attribute__((ext_vector_type(4)));
typedef _Float16 half8 __attribute__((ext_vector_type(8)));
typedef float floatx4 __attribute__((ext_vector_type(4)));

// ---------------------------------------------------------------------------
// K0: x (N,C,H,W) fp32 -> xt2[b=(n,w)][i=h][c] fp16.
// Per (n,h): transpose 128x128 (c,w) -> (w,c). grid=(1024, 2, 2), block=256.
// ---------------------------------------------------------------------------
__global__ void transpose_cvt_k(const float* __restrict__ x, _Float16* __restrict__ xt2) {
  __shared__ float tile[64][65];
  int nh = blockIdx.x;
  int n = nh >> 7, h = nh & 127;
  int c0 = blockIdx.y * 64, w0 = blockIdx.z * 64;
  const float* src = x + (size_t)n * 2097152 + (size_t)h * 128;  // (c,w): src[c*16384 + w]
  _Float16* dst = xt2 + (size_t)n * 2097152 + (size_t)h * 128;   // (w,c): dst[w*16384 + c]
  int lane = threadIdx.x & 63;
  int tr = threadIdx.x >> 6;
#pragma unroll
  for (int rr = tr; rr < 64; rr += 4)
    tile[rr][lane] = src[(size_t)(c0 + rr) * 16384 + w0 + lane];
  __syncthreads();
#pragma unroll
  for (int cc = tr; cc < 64; cc += 4)
    dst[(size_t)(w0 + cc) * 16384 + c0 + lane] = (_Float16)tile[lane][cc];
}

// ---------------------------------------------------------------------------
// K1: qkv16[b][o][i] = fp16( BN( sum_c W[o][c] * xt2[b][i][c] ) )
// f16 MFMA 16x16x32. Block = (b, o-half): C-tile 128(o) x 128(i), K=128.
// ---------------------------------------------------------------------------
__global__ void __launch_bounds__(256, 2) qkv_mfma_kernel(
    const _Float16* __restrict__ xt2, const float* __restrict__ wq,
    const float* __restrict__ qg, const float* __restrict__ qb,
    const float* __restrict__ qm, const float* __restrict__ qv,
    _Float16* __restrict__ qkv16) {
  __shared__ _Float16 As[128][136];
  __shared__ _Float16 Bs[128][136];
  __shared__ float scs[128];
  __shared__ float bis[128];
  int b = blockIdx.x >> 1;
  int oh = blockIdx.x & 1;
  int t = threadIdx.x;

  {
    const float* wbase = wq + (size_t)oh * 128 * 128;
#pragma unroll
    for (int idx = t; idx < 4096; idx += 256) {
      int o = idx >> 5, c4 = (idx & 31) * 4;
      float4 v = *(const float4*)(wbase + (size_t)o * 128 + c4);
      half4 hv;
      hv[0] = (_Float16)v.x;
      hv[1] = (_Float16)v.y;
      hv[2] = (_Float16)v.z;
      hv[3] = (_Float16)v.w;
      *(half4*)(&As[o][c4]) = hv;
    }
  }
  {
    const _Float16* xb = xt2 + (size_t)b * 16384;
#pragma unroll
    for (int idx = t; idx < 2048; idx += 256) {
      int i = idx >> 4, c8 = (idx & 15) * 8;
      half8 v = *(const half8*)(xb + (size_t)i * 128 + c8);
      *(half8*)(&Bs[i][c8]) = v;
    }
  }
  if (t < 128) {
    int o = oh * 128 + t;
    float sc = qg[o] * rsqrtf(qv[o] + EPS);
    scs[t] = sc;
    bis[t] = qb[o] - qm[o] * sc;
  }
  __syncthreads();

  int wv = t >> 6;
  int lane = t & 63;
  int m0 = (wv & 1) * 64;
  int n0 = (wv >> 1) * 64;
  int lrow = lane & 15;
  int quad = lane >> 4;

  floatx4 acc[4][4];
#pragma unroll
  for (int mt = 0; mt < 4; mt++)
#pragma unroll
    for (int nt = 0; nt < 4; nt++)
#pragma unroll
      for (int r = 0; r < 4; r++) acc[mt][nt][r] = 0.f;

#pragma unroll
  for (int k0 = 0; k0 < 128; k0 += 32) {
    half8 af[4], bf[4];
#pragma unroll
    for (int mt = 0; mt < 4; mt++)
      af[mt] = *(const half8*)(&As[m0 + mt * 16 + lrow][k0 + quad * 8]);
#pragma unroll
    for (int nt = 0; nt < 4; nt++)
      bf[nt] = *(const half8*)(&Bs[n0 + nt * 16 + lrow][k0 + quad * 8]);
#pragma unroll
    for (int mt = 0; mt < 4; mt++)
#pragma unroll
      for (int nt = 0; nt < 4; nt++)
        acc[mt][nt] = __builtin_amdgcn_mfma_f32_16x16x32_f16(af[mt], bf[nt], acc[mt][nt], 0, 0, 0);
  }

  _Float16* outb = qkv16 + (size_t)b * 32768 + (size_t)oh * 16384;
#pragma unroll
  for (int mt = 0; mt < 4; mt++) {
#pragma unroll
    for (int r = 0; r < 4; r++) {
      int o_l = m0 + mt * 16 + quad * 4 + r;
      float sc = scs[o_l];
      float bi = bis[o_l];
#pragma unroll
      for (int nt = 0; nt < 4; nt++) {
        int i = n0 + nt * 16 + lrow;
        outb[(size_t)o_l * 128 + i] = (_Float16)fmaf(acc[mt][nt][r], sc, bi);
      }
    }
  }
}

// ---------------------------------------------------------------------------
// K2 (fused with old K3): MFMA attention + out-BN, writes FINAL fp32 output.
// Block = (n, g, wt): 512 threads = 8 waves, each wave handles ONE w
// (w = wt*8 + wave). Per-wave algorithm identical to the verified K2:
//   S^T[j][i] = mfma(A=k^T, B=q^T) with K=8 channels replicated over quads
//   (folded /4 into the scale). Softmax over j via per-lane partial +
//   shfl_xor(16,32). P -> per-wave LDS fp16 -> b128 B-frags for PV (K=128).
// Changes vs old K2:
//   * sim-BN bias dropped (constant over softmax axis j -> cancels exactly)
//   * log2(e) folded into scale, exp2f instead of __expf
//   * O written to olds[c][h][w8] fp16 in LDS; after one barrier the block
//     cooperatively stores float4-of-w -> out[n][g*16+c][h][w] (w-contiguous,
//     full 32B chunks per block => no separate transpose kernel).
// LDS = 32KB (olds) + 8*4.25KB (plds) = 67.6KB -> 2 blocks/CU = 16 waves/CU.
// ---------------------------------------------------------------------------
__global__ void __launch_bounds__(512, 4) attn_mfma_fused_kernel(
    const _Float16* __restrict__ qkv16,
    const float* __restrict__ sg, const float* __restrict__ sb,
    const float* __restrict__ sm, const float* __restrict__ svv,
    const float* __restrict__ og, const float* __restrict__ obt,
    const float* __restrict__ om, const float* __restrict__ ov,
    float* __restrict__ out) {
  __shared__ _Float16 olds[16][128][8];  // [c][h][w8] fp16 = 32KB
  __shared__ _Float16 plds[8][2176];     // per-wave P[i][j], row stride 136 halves
  int bid = blockIdx.x;
  int nn = bid >> 7;         // n
  int g = (bid >> 4) & 7;    // group
  int wt = bid & 15;         // w-tile of 8
  int t = threadIdx.x;
  int wv = t >> 6;           // wave 0..7 -> local w
  int lane = t & 63;
  int ln = lane & 15;
  int q4 = lane >> 4;

  float s_scale = sg[g] * rsqrtf(svv[g] + EPS);
  // /4 for quad replication, *log2(e) for exp2. sim-BN bias cancels in softmax.
  float sc4 = s_scale * 0.25f * 1.44269504f;
  (void)sb;
  (void)sm;

  // out-BN coeffs for this lane's O rows c = q4*4 + r
  float osc[4], obi[4];
#pragma unroll
  for (int r = 0; r < 4; r++) {
    int oc = g * 16 + q4 * 4 + r;
    float s0 = og[oc] * rsqrtf(ov[oc] + EPS);
    osc[r] = s0;
    obi[r] = obt[oc] - om[oc] * s0;
  }

  _Float16* pw = &plds[wv][0];
  int b = nn * 128 + wt * 8 + wv;
  const _Float16* base = qkv16 + (size_t)b * 32768 + (size_t)g * 4096;
  const _Float16* kb = base + 1024;
  const _Float16* vb = base + 2048;

  // k fragments (A-operand), all j-tiles, channels replicated per quad
  half8 kf[8];
#pragma unroll
  for (int jt = 0; jt < 8; jt++)
#pragma unroll
    for (int jj = 0; jj < 8; jj++)
      kf[jt][jj] = kb[jj * 128 + jt * 16 + ln];

  // v fragments (A-operand for PV): lane&15 = c, 8 consecutive j per quad
  half8 vf[4];
#pragma unroll
  for (int ks = 0; ks < 4; ks++)
    vf[ks] = *(const half8*)(vb + (size_t)ln * 128 + ks * 32 + q4 * 8);

  for (int st8 = 0; st8 < 8; st8++) {
    // q fragment (B-operand) for i-strip st8
    half8 qf;
#pragma unroll
    for (int jj = 0; jj < 8; jj++)
      qf[jj] = base[jj * 128 + st8 * 16 + ln];

    // S^T tiles: C[j][i], 8 j-tiles
    floatx4 stt[8];
#pragma unroll
    for (int jt = 0; jt < 8; jt++) {
      floatx4 z = {0.f, 0.f, 0.f, 0.f};
      stt[jt] = __builtin_amdgcn_mfma_f32_16x16x32_f16(kf[jt], qf, z, 0, 0, 0);
    }

    // scale (log2 domain) + column softmax (over j = regs/quads)
    float mx = -1e30f;
#pragma unroll
    for (int jt = 0; jt < 8; jt++)
#pragma unroll
      for (int r = 0; r < 4; r++) {
        stt[jt][r] *= sc4;
        mx = fmaxf(mx, stt[jt][r]);
      }
    mx = fmaxf(mx, __shfl_xor(mx, 16));
    mx = fmaxf(mx, __shfl_xor(mx, 32));

    float ls = 0.f;
#pragma unroll
    for (int jt = 0; jt < 8; jt++)
#pragma unroll
      for (int r = 0; r < 4; r++) {
        float e = exp2f(stt[jt][r] - mx);
        stt[jt][r] = e;
        ls += e;
      }
    ls += __shfl_xor(ls, 16);
    ls += __shfl_xor(ls, 32);

    // P -> LDS fp16: lane holds P[i=ln][j = jt*16 + q4*4 + r], 4 consecutive j
#pragma unroll
    for (int jt = 0; jt < 8; jt++) {
      half4 h;
      h[0] = (_Float16)stt[jt][0];
      h[1] = (_Float16)stt[jt][1];
      h[2] = (_Float16)stt[jt][2];
      h[3] = (_Float16)stt[jt][3];
      *(half4*)(&pw[ln * 136 + jt * 16 + q4 * 4]) = h;
    }

    // PV: O[c][i] = sum_j v[c][j] P[i][j], K=128 in 4 steps
    floatx4 oacc = {0.f, 0.f, 0.f, 0.f};
#pragma unroll
    for (int ks = 0; ks < 4; ks++) {
      half8 pf = *(const half8*)(&pw[ln * 136 + ks * 32 + q4 * 8]);
      oacc = __builtin_amdgcn_mfma_f32_16x16x32_f16(vf[ks], pf, oacc, 0, 0, 0);
    }

    // normalize + out-BN -> staged fp16 in olds[c][h][w]
    float invl = 1.f / ls;
#pragma unroll
    for (int r = 0; r < 4; r++)
      olds[q4 * 4 + r][st8 * 16 + ln][wv] = (_Float16)fmaf(oacc[r] * invl, osc[r], obi[r]);
  }

  __syncthreads();

  // cooperative transposed store: out[n][g*16+c][h][wt*8 + w], float4-of-w
  float* outp = out + ((size_t)nn * 128 + g * 16) * 16384 + wt * 8;
#pragma unroll
  for (int idx = t; idx < 4096; idx += 512) {
    int w4 = idx & 1;
    int h = (idx >> 1) & 127;
    int c = idx >> 8;
    half4 v = *(const half4*)(&olds[c][h][w4 * 4]);
    float4 f;
    f.x = (float)v[0];
    f.y = (float)v[1];
    f.z = (float)v[2];
    f.w = (float)v[3];
    *(float4*)(outp + (size_t)c * 16384 + (size_t)h * 128 + w4 * 4) = f;
  }
}

// ---------------------------------------------------------------------------
extern "C" void kernel_launch(void* const* d_in, const int* in_sizes, int n_in,
                              void* d_out, int out_size, void* d_ws, size_t ws_size,
                              hipStream_t stream) {
  const float* x  = (const float*)d_in[0];
  const float* wq = (const float*)d_in[1];
  const float* qg = (const float*)d_in[2];
  const float* qb = (const float*)d_in[3];
  const float* qm = (const float*)d_in[4];
  const float* qv = (const float*)d_in[5];
  const float* sg = (const float*)d_in[6];
  const float* sb = (const float*)d_in[7];
  const float* sm = (const float*)d_in[8];
  const float* sv = (const float*)d_in[9];
  const float* og = (const float*)d_in[10];
  const float* ob = (const float*)d_in[11];
  const float* om = (const float*)d_in[12];
  const float* ov = (const float*)d_in[13];
  float* out = (float*)d_out;

  // workspace: qkv16 64MB | xt2 32MB  (96 MB total; svh no longer needed)
  _Float16* qkv16 = (_Float16*)d_ws;
  _Float16* xt2 = qkv16 + (size_t)1024 * 256 * 128;

  // K0: x -> xt2[b][i][c] fp16
  transpose_cvt_k<<<dim3(1024, 2, 2), 256, 0, stream>>>(x, xt2);
  // K1: f16 MFMA GEMM + BN -> qkv16[b][o][i] fp16
  qkv_mfma_kernel<<<2048, 256, 0, stream>>>(xt2, wq, qg, qb, qm, qv, qkv16);
  // K2: MFMA attention + out-BN + final transpose -> out fp32 (N,O,H,W)
  attn_mfma_fused_kernel<<<1024, 512, 0, stream>>>(qkv16, sg, sb, sm, sv,
                                                   og, ob, om, ov, out);
}